// Round 1
// baseline (79.947 us; speedup 1.0000x reference)
//
#include <hip/hip_runtime.h>

// out[b][h] = relu(input[b][h] + hx[b][h] * w[h]); B=16384, H=2048, f32.
// Memory-bound elementwise: float4 vectorization, grid-stride loop.

__global__ void indrnn_relu_kernel(const float4* __restrict__ in,
                                   const float4* __restrict__ hx,
                                   const float4* __restrict__ w,   // H/4 = 512 float4
                                   float4* __restrict__ out,
                                   int n4) {
    const int stride = gridDim.x * blockDim.x;
    for (int i = blockIdx.x * blockDim.x + threadIdx.x; i < n4; i += stride) {
        float4 a = in[i];
        float4 b = hx[i];
        float4 wv = w[i & 511];   // (i*4) % 2048 / 4  == i % 512
        float4 r;
        r.x = fmaxf(0.0f, fmaf(b.x, wv.x, a.x));
        r.y = fmaxf(0.0f, fmaf(b.y, wv.y, a.y));
        r.z = fmaxf(0.0f, fmaf(b.z, wv.z, a.z));
        r.w = fmaxf(0.0f, fmaf(b.w, wv.w, a.w));
        out[i] = r;
    }
}

extern "C" void kernel_launch(void* const* d_in, const int* in_sizes, int n_in,
                              void* d_out, int out_size, void* d_ws, size_t ws_size,
                              hipStream_t stream) {
    const float4* in  = (const float4*)d_in[0];   // input  (B*H f32)
    const float4* hx  = (const float4*)d_in[1];   // hx     (B*H f32)
    const float4* w   = (const float4*)d_in[2];   // weight (H f32)
    float4* out = (float4*)d_out;

    const int n4 = out_size / 4;                  // 33_554_432 / 4 = 8_388_608
    const int block = 256;
    int grid = (n4 + block - 1) / block;
    if (grid > 2048) grid = 2048;                 // grid-stride the rest
    indrnn_relu_kernel<<<grid, block, 0, stream>>>(in, hx, w, out, n4);
}

// Round 3
// 65.639 us; speedup vs baseline: 1.2180x; 1.2180x over previous
//
#include <hip/hip_runtime.h>

// out[b][h] = relu(input[b][h] + hx[b][h] * w[h]); B=16384, H=2048, f32.
// Memory-bound elementwise. 16B vector loads, nontemporal stores (output is
// write-once; keep the 256 MiB of inputs resident in Infinity Cache),
// 2x unroll for memory-level parallelism.
// Use clang native vector type: __builtin_nontemporal_store rejects the
// HIP_vector_type<float,4> class.

typedef float f32x4 __attribute__((ext_vector_type(4)));

__global__ void indrnn_relu_kernel(const f32x4* __restrict__ in,
                                   const f32x4* __restrict__ hx,
                                   const f32x4* __restrict__ w,   // H/4 = 512 vecs
                                   f32x4* __restrict__ out,
                                   int n4) {
    const int stride = gridDim.x * blockDim.x;   // multiple of 512 by construction
    int i = blockIdx.x * blockDim.x + threadIdx.x;

    for (; i + stride < n4; i += 2 * stride) {
        // issue all 4 independent loads before any compute (MLP)
        f32x4 a0 = in[i];
        f32x4 b0 = hx[i];
        f32x4 a1 = in[i + stride];
        f32x4 b1 = hx[i + stride];
        f32x4 wv = w[i & 511];   // stride % 512 == 0 -> same weight slot for both

        f32x4 r0, r1;
        #pragma unroll
        for (int j = 0; j < 4; ++j) {
            r0[j] = fmaxf(0.0f, fmaf(b0[j], wv[j], a0[j]));
            r1[j] = fmaxf(0.0f, fmaf(b1[j], wv[j], a1[j]));
        }

        __builtin_nontemporal_store(r0, &out[i]);
        __builtin_nontemporal_store(r1, &out[i + stride]);
    }
    // tail (not taken for B*H/4 = 8388608 with stride 524288, kept for safety)
    for (; i < n4; i += stride) {
        f32x4 a = in[i];
        f32x4 b = hx[i];
        f32x4 wv = w[i & 511];
        f32x4 r;
        #pragma unroll
        for (int j = 0; j < 4; ++j)
            r[j] = fmaxf(0.0f, fmaf(b[j], wv[j], a[j]));
        __builtin_nontemporal_store(r, &out[i]);
    }
}

extern "C" void kernel_launch(void* const* d_in, const int* in_sizes, int n_in,
                              void* d_out, int out_size, void* d_ws, size_t ws_size,
                              hipStream_t stream) {
    const f32x4* in  = (const f32x4*)d_in[0];   // input  (B*H f32)
    const f32x4* hx  = (const f32x4*)d_in[1];   // hx     (B*H f32)
    const f32x4* w   = (const f32x4*)d_in[2];   // weight (H f32)
    f32x4* out = (f32x4*)d_out;

    const int n4 = out_size / 4;                // 33_554_432 / 4 = 8_388_608
    const int block = 256;
    int grid = 2048;                            // 8 blocks/CU; grid-stride x16
    indrnn_relu_kernel<<<grid, block, 0, stream>>>(in, hx, w, out, n4);
}